// Round 4
// baseline (740.210 us; speedup 1.0000x reference)
//
#include <hip/hip_runtime.h>
#include <hip/hip_bf16.h>

#define NQ 20
#define NLAY 51            // N_LAYER+1
#define FEAT 128
#define BATCH 128
#define NN (BATCH * NQ * NLAY)   // 130560
#define NE 524288
#define NPAIR (BATCH * NQ * NQ)  // 51200

typedef _Float16 half8 __attribute__((ext_vector_type(8)));
typedef float floatx4 __attribute__((ext_vector_type(4)));

__device__ __forceinline__ float lrelu(float v) { return v >= 0.f ? v : 0.01f * v; }

// ---------------- embedding gather ----------------
__global__ void k_embed(const int* __restrict__ x, const float* __restrict__ emb,
                        float* __restrict__ h) {
    int t = blockIdx.x * 256 + threadIdx.x;
    int r = t >> 5, c4 = t & 31;
    int tok = x[r];
    ((float4*)(h + (size_t)r * FEAT))[c4] = ((const float4*)(emb + (size_t)tok * FEAT))[c4];
}

// ---------------- CSR build ----------------
__global__ void k_count(const int* __restrict__ dst, int* __restrict__ cnt) {
    int e = blockIdx.x * 256 + threadIdx.x;
    atomicAdd(&cnt[dst[e]], 1);
}

__global__ void k_partial(const int* __restrict__ cnt, int* __restrict__ part) {
    __shared__ int sm[256];
    int t = threadIdx.x;
    sm[t] = cnt[blockIdx.x * 256 + t];
    __syncthreads();
    for (int s = 128; s > 0; s >>= 1) {
        if (t < s) sm[t] += sm[t + s];
        __syncthreads();
    }
    if (t == 0) part[blockIdx.x] = sm[0];
}

__global__ void k_scanpart(const int* __restrict__ part, int* __restrict__ pscan, int nb) {
    __shared__ int sm[512];
    int t = threadIdx.x;
    int v = (t < nb) ? part[t] : 0;
    sm[t] = v;
    __syncthreads();
    for (int s = 1; s < 512; s <<= 1) {
        int add = (t >= s) ? sm[t - s] : 0;
        __syncthreads();
        sm[t] += add;
        __syncthreads();
    }
    if (t < nb) pscan[t] = sm[t] - v;   // exclusive
}

// offsets + dinv fused
__global__ void k_offsets(const int* __restrict__ cnt, const int* __restrict__ pscan,
                          int* __restrict__ offs, float* __restrict__ dinv) {
    __shared__ int sm[256];
    int t = threadIdx.x, g = blockIdx.x * 256 + t;
    int v = cnt[g];
    sm[t] = v;
    __syncthreads();
    for (int s = 1; s < 256; s <<= 1) {
        int add = (t >= s) ? sm[t - s] : 0;
        __syncthreads();
        sm[t] += add;
        __syncthreads();
    }
    offs[g] = pscan[blockIdx.x] + sm[t] - v;
    dinv[g] = rsqrtf((float)(v + 1));  // +1 self loop
}

__global__ void k_fill(const int* __restrict__ src, const int* __restrict__ dst,
                       const int* __restrict__ offs, int* __restrict__ fill,
                       const float* __restrict__ dinv,
                       int* __restrict__ csr, float* __restrict__ csrw) {
    int e = blockIdx.x * 256 + threadIdx.x;
    int d = dst[e];
    int s = src[e];
    int pos = offs[d] + atomicAdd(&fill[d], 1);
    csr[pos] = s;
    csrw[pos] = dinv[s];
}

// ---------------- weight transpose + fp16 hi/lo split, PACKED MFMA-fragment layout -------
// Packed: element index = ((ntile*(K/32) + kblk)*64 + lane)*8 + j
//   col = ntile*16 + (lane&15), k = kblk*32 + (lane>>4)*8 + j.
#define OFF_GCN 0                 // 5 x K=128 N=128
#define OFF_P0  81920             // combined mw0: K=128 N=512
#define OFF_M1  147456            // mw1: K=256 N=128
#define OFF_M2  180224            // mw2: K=128 N=128
#define OFF_M3  196608            // mw3: K=128 N=64
#define OFF_M4  204800            // mw4: K=64  N=64
#define TS_TOTAL 208896

__global__ void k_tsplit_all(const float* __restrict__ gw, const float* __restrict__ mw0,
                             const float* __restrict__ mw1, const float* __restrict__ mw2,
                             const float* __restrict__ mw3, const float* __restrict__ mw4,
                             _Float16* __restrict__ hi, _Float16* __restrict__ lo) {
    int idx = blockIdx.x * 256 + threadIdx.x;
    const float* src;
    int K, N, rel;
    bool p0 = false;
    if (idx < OFF_P0) {
        int L = (idx - OFF_GCN) >> 14; rel = (idx - OFF_GCN) & 16383;
        src = gw + L * 16384; K = 128; N = 128;
    } else if (idx < OFF_M1) {
        rel = idx - OFF_P0; src = mw0; K = 128; N = 512; p0 = true;
    } else if (idx < OFF_M2) {
        rel = idx - OFF_M1;  src = mw1; K = 256; N = 128;
    } else if (idx < OFF_M3) {
        rel = idx - OFF_M2;  src = mw2; K = 128; N = 128;
    } else if (idx < OFF_M4) {
        rel = idx - OFF_M3;  src = mw3; K = 128; N = 64;
    } else {
        rel = idx - OFF_M4;  src = mw4; K = 64;  N = 64;
    }
    int kblks = K >> 5;
    int j = rel & 7;
    int lane = (rel >> 3) & 63;
    int t2 = rel >> 9;
    int kblk = t2 % kblks;
    int ntile = t2 / kblks;
    int col = ntile * 16 + (lane & 15);
    int k = kblk * 32 + ((lane >> 4) << 3) + j;
    float f;
    if (p0) {
        f = (col < 256) ? src[k * 256 + col] : src[(k + 128) * 256 + (col - 256)];
    } else {
        f = src[k * N + col];
    }
    _Float16 h = (_Float16)f;
    hi[idx] = h;
    lo[idx] = (_Float16)(f - (float)h);
}

// ---------------- split-fp16 MFMA GEMM (gemm0 + pair MLP) ----------------
template <int NT_N, bool LEAKY, bool BIAS, bool P0SPLIT, bool FUSEA>
__launch_bounds__(256, 2)
__global__ void hgemm(const float* __restrict__ A,
                      const float* __restrict__ FA, const float* __restrict__ FB,
                      const _Float16* __restrict__ Bh, const _Float16* __restrict__ Bl,
                      const float* __restrict__ bias,
                      float* __restrict__ C, float* __restrict__ C2,
                      int N, int K) {
    const int KB = K >> 5;
    const int lane = threadIdx.x & 63;
    const int wid = threadIdx.x >> 6;
    const int lm = lane & 15, lq = lane >> 4;
    const int m0 = blockIdx.x * 128 + wid * 32;
    const int n0t = blockIdx.y * NT_N;

    const float* arow[2];
    const float* brow[2];
#pragma unroll
    for (int mt = 0; mt < 2; mt++) {
        int row = m0 + mt * 16 + lm;
        if (FUSEA) {
            int b = row / (NQ * NQ);
            int rr = row - b * (NQ * NQ);
            int i = rr / NQ;
            int j = rr - i * NQ;
            arow[mt] = FA + (size_t)(b * NQ + i) * 256;
            brow[mt] = FB + (size_t)(b * NQ + j) * 256;
        } else {
            arow[mt] = A + (size_t)row * K;
        }
    }

    floatx4 acc[2][NT_N];
#pragma unroll
    for (int mt = 0; mt < 2; mt++)
#pragma unroll
        for (int nt = 0; nt < NT_N; nt++) acc[mt][nt] = (floatx4)0.f;

    for (int kb = 0; kb < KB; kb++) {
        const int k0 = kb * 32 + lq * 8;
        half8 ahi[2], alo[2];
#pragma unroll
        for (int mt = 0; mt < 2; mt++) {
            floatx4 av0, av1;
            if (FUSEA) {
                floatx4 fa0 = *(const floatx4*)(arow[mt] + k0);
                floatx4 fa1 = *(const floatx4*)(arow[mt] + k0 + 4);
                floatx4 fb0 = *(const floatx4*)(brow[mt] + k0);
                floatx4 fb1 = *(const floatx4*)(brow[mt] + k0 + 4);
#pragma unroll
                for (int q = 0; q < 4; q++) {
                    av0[q] = lrelu(fa0[q] + fb0[q]);
                    av1[q] = lrelu(fa1[q] + fb1[q]);
                }
            } else {
                av0 = *(const floatx4*)(arow[mt] + k0);
                av1 = *(const floatx4*)(arow[mt] + k0 + 4);
            }
#pragma unroll
            for (int q = 0; q < 4; q++) {
                _Float16 h0 = (_Float16)av0[q];
                ahi[mt][q] = h0;
                alo[mt][q] = (_Float16)(av0[q] - (float)h0);
                _Float16 h1 = (_Float16)av1[q];
                ahi[mt][4 + q] = h1;
                alo[mt][4 + q] = (_Float16)(av1[q] - (float)h1);
            }
        }
#pragma unroll
        for (int nt = 0; nt < NT_N; nt++) {
            size_t boff = (((size_t)(n0t + nt) * KB + kb) * 64 + lane) * 8;
            half8 bhi = *(const half8*)(Bh + boff);
            half8 blo = *(const half8*)(Bl + boff);
#pragma unroll
            for (int mt = 0; mt < 2; mt++) {
                acc[mt][nt] = __builtin_amdgcn_mfma_f32_16x16x32_f16(ahi[mt], bhi, acc[mt][nt], 0, 0, 0);
                acc[mt][nt] = __builtin_amdgcn_mfma_f32_16x16x32_f16(ahi[mt], blo, acc[mt][nt], 0, 0, 0);
                acc[mt][nt] = __builtin_amdgcn_mfma_f32_16x16x32_f16(alo[mt], bhi, acc[mt][nt], 0, 0, 0);
            }
        }
    }

#pragma unroll
    for (int nt = 0; nt < NT_N; nt++) {
        int col = (n0t + nt) * 16 + lm;
        float bv = (BIAS || P0SPLIT) ? bias[col < 256 ? col : 0] : 0.f;
#pragma unroll
        for (int mt = 0; mt < 2; mt++) {
#pragma unroll
            for (int r = 0; r < 4; r++) {
                int row = m0 + mt * 16 + lq * 4 + r;
                float val = acc[mt][nt][r];
                if (P0SPLIT) {
                    if (col < 256) C[(size_t)row * 256 + col] = val + bv;
                    else C2[(size_t)row * 256 + col - 256] = val;
                } else {
                    if (BIAS) val += bv;
                    if (LEAKY) val = lrelu(val);
                    C[(size_t)row * N + col] = val;
                }
            }
        }
    }
}

// ---------------- FUSED: agg(hw_in)+bias -> lrelu -> +h (residual, in-place) -> @W -> hw_out
// Phase 1: 8 half-waves aggregate the block's 128 rows into LDS (XOR-swizzled float4)
//          and write the updated h rows to global (needed as next residual).
// Phase 2: MFMA GEMM with A-fragments read from LDS. N=128, K=128 fixed.
__global__ __launch_bounds__(256, 2) void k_fused(
        const float* __restrict__ hw_in, float* __restrict__ h,
        const int* __restrict__ csr, const float* __restrict__ csrw,
        const int* __restrict__ offs, const int* __restrict__ cnt,
        const float* __restrict__ dinv, const float* __restrict__ gbias,
        const _Float16* __restrict__ Bh, const _Float16* __restrict__ Bl,
        float* __restrict__ hw_out) {
    __shared__ float4 sA[128][32];   // 64 KB, col swizz: c4 ^ (row & 7)
    const int tid = threadIdx.x;
    const int sl = tid & 31;
    const int hwid = tid >> 5;
    const int base = blockIdx.x * 128;
    float4 bv = ((const float4*)gbias)[sl];

    // ---- phase 1: aggregate 16 rows per half-wave, 2 rows interleaved ----
    for (int i = 0; i < 16; i += 2) {
        int r0 = hwid * 16 + i, r1 = r0 + 1;
        int n0 = base + r0, n1 = base + r1;
        float di0 = dinv[n0], di1 = dinv[n1];
        int off0 = offs[n0], deg0 = cnt[n0];
        int off1 = offs[n1], deg1 = cnt[n1];
        int d0c = max(deg0 - 1, 0), d1c = max(deg1 - 1, 0);
        float4 v0 = ((const float4*)(hw_in + (size_t)n0 * FEAT))[sl];
        float4 v1 = ((const float4*)(hw_in + (size_t)n1 * FEAT))[sl];
        float s20 = di0 * di0, s21 = di1 * di1;
        float a0x = v0.x * s20, a0y = v0.y * s20, a0z = v0.z * s20, a0w = v0.w * s20;
        float a1x = v1.x * s21, a1y = v1.y * s21, a1z = v1.z * s21, a1w = v1.w * s21;
        int dm = max(deg0, deg1);
        for (int e = 0; e < dm; e += 4) {
            int c00 = min(e, d0c), c01 = min(e + 1, d0c), c02 = min(e + 2, d0c), c03 = min(e + 3, d0c);
            int c10 = min(e, d1c), c11 = min(e + 1, d1c), c12 = min(e + 2, d1c), c13 = min(e + 3, d1c);
            int s00 = csr[off0 + c00], s01 = csr[off0 + c01], s02 = csr[off0 + c02], s03 = csr[off0 + c03];
            int s10 = csr[off1 + c10], s11 = csr[off1 + c11], s12 = csr[off1 + c12], s13 = csr[off1 + c13];
            float w00 = (e     < deg0) ? csrw[off0 + c00] * di0 : 0.f;
            float w01 = (e + 1 < deg0) ? csrw[off0 + c01] * di0 : 0.f;
            float w02 = (e + 2 < deg0) ? csrw[off0 + c02] * di0 : 0.f;
            float w03 = (e + 3 < deg0) ? csrw[off0 + c03] * di0 : 0.f;
            float w10 = (e     < deg1) ? csrw[off1 + c10] * di1 : 0.f;
            float w11 = (e + 1 < deg1) ? csrw[off1 + c11] * di1 : 0.f;
            float w12 = (e + 2 < deg1) ? csrw[off1 + c12] * di1 : 0.f;
            float w13 = (e + 3 < deg1) ? csrw[off1 + c13] * di1 : 0.f;
            float4 u00 = ((const float4*)(hw_in + (size_t)s00 * FEAT))[sl];
            float4 u01 = ((const float4*)(hw_in + (size_t)s01 * FEAT))[sl];
            float4 u02 = ((const float4*)(hw_in + (size_t)s02 * FEAT))[sl];
            float4 u03 = ((const float4*)(hw_in + (size_t)s03 * FEAT))[sl];
            float4 u10 = ((const float4*)(hw_in + (size_t)s10 * FEAT))[sl];
            float4 u11 = ((const float4*)(hw_in + (size_t)s11 * FEAT))[sl];
            float4 u12 = ((const float4*)(hw_in + (size_t)s12 * FEAT))[sl];
            float4 u13 = ((const float4*)(hw_in + (size_t)s13 * FEAT))[sl];
            a0x += u00.x * w00 + u01.x * w01 + u02.x * w02 + u03.x * w03;
            a0y += u00.y * w00 + u01.y * w01 + u02.y * w02 + u03.y * w03;
            a0z += u00.z * w00 + u01.z * w01 + u02.z * w02 + u03.z * w03;
            a0w += u00.w * w00 + u01.w * w01 + u02.w * w02 + u03.w * w03;
            a1x += u10.x * w10 + u11.x * w11 + u12.x * w12 + u13.x * w13;
            a1y += u10.y * w10 + u11.y * w11 + u12.y * w12 + u13.y * w13;
            a1z += u10.z * w10 + u11.z * w11 + u12.z * w12 + u13.z * w13;
            a1w += u10.w * w10 + u11.w * w11 + u12.w * w12 + u13.w * w13;
        }
        float4 ho0 = ((const float4*)(h + (size_t)n0 * FEAT))[sl];
        float4 ho1 = ((const float4*)(h + (size_t)n1 * FEAT))[sl];
        float4 res0, res1;
        res0.x = lrelu(a0x + bv.x) + ho0.x;
        res0.y = lrelu(a0y + bv.y) + ho0.y;
        res0.z = lrelu(a0z + bv.z) + ho0.z;
        res0.w = lrelu(a0w + bv.w) + ho0.w;
        res1.x = lrelu(a1x + bv.x) + ho1.x;
        res1.y = lrelu(a1y + bv.y) + ho1.y;
        res1.z = lrelu(a1z + bv.z) + ho1.z;
        res1.w = lrelu(a1w + bv.w) + ho1.w;
        sA[r0][sl ^ (r0 & 7)] = res0;
        sA[r1][sl ^ (r1 & 7)] = res1;
        ((float4*)(h + (size_t)n0 * FEAT))[sl] = res0;
        ((float4*)(h + (size_t)n1 * FEAT))[sl] = res1;
    }
    __syncthreads();

    // ---- phase 2: GEMM (N=128, K=128), A from LDS ----
    const int lane = tid & 63;
    const int wid = tid >> 6;
    const int lm = lane & 15, lq = lane >> 4;
    const int mloc = wid * 32;

    floatx4 acc[2][8];
#pragma unroll
    for (int mt = 0; mt < 2; mt++)
#pragma unroll
        for (int nt = 0; nt < 8; nt++) acc[mt][nt] = (floatx4)0.f;

#pragma unroll
    for (int kb = 0; kb < 4; kb++) {
        const int c4 = kb * 8 + lq * 2;
        half8 ahi[2], alo[2];
#pragma unroll
        for (int mt = 0; mt < 2; mt++) {
            int row = mloc + mt * 16 + lm;
            float4 av0 = sA[row][c4 ^ (row & 7)];
            float4 av1 = sA[row][(c4 + 1) ^ (row & 7)];
            const float* p0 = &av0.x;
            const float* p1 = &av1.x;
#pragma unroll
            for (int q = 0; q < 4; q++) {
                _Float16 h0 = (_Float16)p0[q];
                ahi[mt][q] = h0;
                alo[mt][q] = (_Float16)(p0[q] - (float)h0);
                _Float16 h1 = (_Float16)p1[q];
                ahi[mt][4 + q] = h1;
                alo[mt][4 + q] = (_Float16)(p1[q] - (float)h1);
            }
        }
#pragma unroll
        for (int nt = 0; nt < 8; nt++) {
            size_t boff = (((size_t)nt * 4 + kb) * 64 + lane) * 8;
            half8 bhi = *(const half8*)(Bh + boff);
            half8 blo = *(const half8*)(Bl + boff);
#pragma unroll
            for (int mt = 0; mt < 2; mt++) {
                acc[mt][nt] = __builtin_amdgcn_mfma_f32_16x16x32_f16(ahi[mt], bhi, acc[mt][nt], 0, 0, 0);
                acc[mt][nt] = __builtin_amdgcn_mfma_f32_16x16x32_f16(ahi[mt], blo, acc[mt][nt], 0, 0, 0);
                acc[mt][nt] = __builtin_amdgcn_mfma_f32_16x16x32_f16(alo[mt], bhi, acc[mt][nt], 0, 0, 0);
            }
        }
    }

#pragma unroll
    for (int nt = 0; nt < 8; nt++) {
        int col = nt * 16 + lm;
#pragma unroll
        for (int mt = 0; mt < 2; mt++) {
#pragma unroll
            for (int r = 0; r < 4; r++) {
                int row = base + mloc + mt * 16 + lq * 4 + r;
                hw_out[(size_t)row * 128 + col] = acc[mt][nt][r];
            }
        }
    }
}

// ---------------- selective final agg: only the 2560 pair-phase rows -> hq ----------------
__global__ void k_aggq(const float* __restrict__ hw_in, const float* __restrict__ h,
                       const int* __restrict__ csr, const float* __restrict__ csrw,
                       const int* __restrict__ offs, const int* __restrict__ cnt,
                       const float* __restrict__ dinv, const float* __restrict__ gbias,
                       float* __restrict__ hq) {
    int tid = threadIdx.x;
    int sl = tid & 31;
    int q = blockIdx.x * 8 + (tid >> 5);   // 0..2559
    int b = q / NQ, i = q - b * NQ;
    int node = b * (NQ * NLAY) + i;
    float di = dinv[node];
    int off = offs[node], deg = cnt[node];
    float s2 = di * di;
    float4 v = ((const float4*)(hw_in + (size_t)node * FEAT))[sl];
    float ax = v.x * s2, ay = v.y * s2, az = v.z * s2, aw = v.w * s2;
    for (int e = 0; e < deg; e += 4) {
        int e0 = e, e1 = min(e + 1, deg - 1), e2 = min(e + 2, deg - 1), e3 = min(e + 3, deg - 1);
        int s0i = csr[off + e0], s1i = csr[off + e1], s2i = csr[off + e2], s3i = csr[off + e3];
        float w0 = csrw[off + e0] * di;
        float w1 = (e + 1 < deg) ? csrw[off + e1] * di : 0.f;
        float w2 = (e + 2 < deg) ? csrw[off + e2] * di : 0.f;
        float w3 = (e + 3 < deg) ? csrw[off + e3] * di : 0.f;
        float4 u0 = ((const float4*)(hw_in + (size_t)s0i * FEAT))[sl];
        float4 u1 = ((const float4*)(hw_in + (size_t)s1i * FEAT))[sl];
        float4 u2 = ((const float4*)(hw_in + (size_t)s2i * FEAT))[sl];
        float4 u3 = ((const float4*)(hw_in + (size_t)s3i * FEAT))[sl];
        ax += u0.x * w0 + u1.x * w1 + u2.x * w2 + u3.x * w3;
        ay += u0.y * w0 + u1.y * w1 + u2.y * w2 + u3.y * w3;
        az += u0.z * w0 + u1.z * w1 + u2.z * w2 + u3.z * w3;
        aw += u0.w * w0 + u1.w * w1 + u2.w * w2 + u3.w * w3;
    }
    float4 bv = ((const float4*)gbias)[sl];
    float4 ho = ((const float4*)(h + (size_t)node * FEAT))[sl];
    // layer 4: no leaky, residual
    ((float4*)(hq + (size_t)q * FEAT))[sl] =
        make_float4(ax + bv.x + ho.x, ay + bv.y + ho.y, az + bv.z + ho.z, aw + bv.w + ho.w);
}

// ---------------- last layer + symmetrize, one block per batch ----------------
__global__ void k_lastsym(const float* __restrict__ X4, const float* __restrict__ mw5,
                          const float* __restrict__ mb5, float* __restrict__ out) {
    __shared__ float w[64];
    __shared__ float sm[NQ * NQ];
    int t = threadIdx.x;
    if (t < 64) w[t] = mw5[t];
    __syncthreads();
    int b = blockIdx.x;
    for (int p = t; p < NQ * NQ; p += 256) {
        const float4* row = (const float4*)(X4 + (size_t)(b * NQ * NQ + p) * 64);
        float s = 0.f;
#pragma unroll
        for (int k4 = 0; k4 < 16; k4++) {
            float4 v = row[k4];
            s += v.x * w[k4 * 4] + v.y * w[k4 * 4 + 1] + v.z * w[k4 * 4 + 2] + v.w * w[k4 * 4 + 3];
        }
        sm[p] = s + mb5[0];
    }
    __syncthreads();
    for (int r = t; r < NQ * NQ; r += 256) {
        int i = r / NQ, j = r % NQ;
        out[(size_t)b * NQ * NQ + r] = 0.5f * (sm[r] + sm[j * NQ + i]);
    }
}

extern "C" void kernel_launch(void* const* d_in, const int* in_sizes, int n_in,
                              void* d_out, int out_size, void* d_ws, size_t ws_size,
                              hipStream_t stream) {
    const int* x = (const int*)d_in[0];
    const int* ei = (const int*)d_in[1];
    const int* e_src = ei;
    const int* e_dst = ei + NE;
    const float* emb = (const float*)d_in[2];
    const float* gw = (const float*)d_in[3];   // [5,128,128]
    const float* gb = (const float*)d_in[4];   // [5,128]
    const float* mw0 = (const float*)d_in[5];
    const float* mb0 = (const float*)d_in[6];
    const float* mw1 = (const float*)d_in[7];
    const float* mb1 = (const float*)d_in[8];
    const float* mw2 = (const float*)d_in[9];
    const float* mb2 = (const float*)d_in[10];
    const float* mw3 = (const float*)d_in[11];
    const float* mb3 = (const float*)d_in[12];
    const float* mw4 = (const float*)d_in[13];
    const float* mb4 = (const float*)d_in[14];
    const float* mw5 = (const float*)d_in[15];
    const float* mb5 = (const float*)d_in[16];
    float* out = (float*)d_out;

    float* wsf = (float*)d_ws;
    size_t o = 0;
    const size_t HSZ = (size_t)NN * FEAT;             // 16,711,680
    float* h   = wsf + o; o += HSZ;
    float* hwA = wsf + o; o += HSZ;
    float* hwB = wsf + o; o += HSZ;
    int* cnt  = (int*)(wsf + o); o += NN;
    int* fill = (int*)(wsf + o); o += NN;   // adjacent to cnt -> single memset
    int* offs = (int*)(wsf + o); o += NN;
    int* csr  = (int*)(wsf + o); o += NE + 8;   // +8: clamped-index slop
    float* csrw = wsf + o; o += NE + 8;
    float* dinv = wsf + o; o += NN;
    int* part  = (int*)(wsf + o); o += 512;
    int* pscan = (int*)(wsf + o); o += 512;
    float* hq = wsf + o; o += (size_t)BATCH * NQ * FEAT;     // 327,680
    float* Abuf = wsf + o; o += (size_t)BATCH * NQ * 256;    // 655,360
    float* Bbuf = wsf + o; o += (size_t)BATCH * NQ * 256;    // 655,360
    _Float16* bt_hi = (_Float16*)(wsf + o); o += (TS_TOTAL + 2) / 2;
    _Float16* bt_lo = (_Float16*)(wsf + o); o += (TS_TOTAL + 2) / 2;
    // pair-phase aliases (buffers dead by then)
    float* X1 = hwB;                        // 51200*128
    float* X2 = hwB + (size_t)NPAIR * 128;  // 51200*128
    float* X3 = h;                          // 51200*64
    float* X4 = h + (size_t)NPAIR * 64;     // 51200*64

    const int NB = NN / 256;  // 510

    // --- weight transpose+split+pack ---
    k_tsplit_all<<<TS_TOTAL / 256, 256, 0, stream>>>(gw, mw0, mw1, mw2, mw3, mw4, bt_hi, bt_lo);

    // --- CSR build ---
    hipMemsetAsync(cnt, 0, 2 * NN * sizeof(int), stream);  // cnt + fill
    k_count<<<NE / 256, 256, 0, stream>>>(e_dst, cnt);
    k_partial<<<NB, 256, 0, stream>>>(cnt, part);
    k_scanpart<<<1, 512, 0, stream>>>(part, pscan, NB);
    k_offsets<<<NB, 256, 0, stream>>>(cnt, pscan, offs, dinv);
    k_fill<<<NE / 256, 256, 0, stream>>>(e_src, e_dst, offs, fill, dinv, csr, csrw);

    // --- embedding -> h0 ---
    k_embed<<<(NN * 32) / 256, 256, 0, stream>>>(x, emb, h);

    // --- gemm0: hw0 = h0 @ W0 ---
    hgemm<8, false, false, false, false><<<dim3(NN / 128, 1), 256, 0, stream>>>(
        h, nullptr, nullptr, bt_hi + OFF_GCN, bt_lo + OFF_GCN, nullptr, hwA, nullptr, FEAT, FEAT);

    // --- fused layers: agg L, residual (h in-place), gemm W_{L+1} ---
    // L=0: hwA -> hwB ; L=1: hwB -> hwA ; L=2: hwA -> hwB ; L=3: hwB -> hwA (=hw4)
    float* hwin = hwA;
    float* hwout = hwB;
    for (int L = 0; L < 4; L++) {
        k_fused<<<NN / 128, 256, 0, stream>>>(
            hwin, h, csr, csrw, offs, cnt, dinv, gb + (size_t)L * FEAT,
            bt_hi + OFF_GCN + (L + 1) * 16384, bt_lo + OFF_GCN + (L + 1) * 16384, hwout);
        float* t = hwin; hwin = hwout; hwout = t;
    }
    // hw4 in hwin (== hwA), h holds h4

    // --- selective final agg (layer 4, only pair-phase rows) -> hq ---
    k_aggq<<<(BATCH * NQ) / 8, 256, 0, stream>>>(hwin, h, csr, csrw, offs, cnt, dinv,
                                                 gb + 4 * (size_t)FEAT, hq);

    // --- pair MLP ---
    // combined P0: Abuf = hq@mw0_top + mb0 ; Bbuf = hq@mw0_bot   (M=2560, K=128, N=512)
    hgemm<8, false, false, true, false><<<dim3(20, 4), 256, 0, stream>>>(
        hq, nullptr, nullptr, bt_hi + OFF_P0, bt_lo + OFF_P0, mb0, Abuf, Bbuf, 512, 128);
    // L1 fused pair0: A[p,:] = lrelu(Abuf[b,i,:] + Bbuf[b,j,:]) ; [51200,256]@[256,128]
    hgemm<8, true, true, false, true><<<dim3(NPAIR / 128, 1), 256, 0, stream>>>(
        nullptr, Abuf, Bbuf, bt_hi + OFF_M1, bt_lo + OFF_M1, mb1, X1, nullptr, 128, 256);
    // L2: [51200,128] @ [128,128]
    hgemm<8, true, true, false, false><<<dim3(NPAIR / 128, 1), 256, 0, stream>>>(
        X1, nullptr, nullptr, bt_hi + OFF_M2, bt_lo + OFF_M2, mb2, X2, nullptr, 128, 128);
    // L3: [51200,128] @ [128,64]
    hgemm<4, true, true, false, false><<<dim3(NPAIR / 128, 1), 256, 0, stream>>>(
        X2, nullptr, nullptr, bt_hi + OFF_M3, bt_lo + OFF_M3, mb3, X3, nullptr, 64, 128);
    // L4: [51200,64] @ [64,64]
    hgemm<4, true, true, false, false><<<dim3(NPAIR / 128, 1), 256, 0, stream>>>(
        X3, nullptr, nullptr, bt_hi + OFF_M4, bt_lo + OFF_M4, mb4, X4, nullptr, 64, 64);
    // L5 + symmetrize
    k_lastsym<<<BATCH, 256, 0, stream>>>(X4, mw5, mb5, out);
}

// Round 6
// 664.251 us; speedup vs baseline: 1.1144x; 1.1144x over previous
//
#include <hip/hip_runtime.h>
#include <hip/hip_bf16.h>

#define NQ 20
#define NLAY 51            // N_LAYER+1
#define FEAT 128
#define BATCH 128
#define NN (BATCH * NQ * NLAY)   // 130560
#define NE 524288
#define NPAIR (BATCH * NQ * NQ)  // 51200

typedef _Float16 half8 __attribute__((ext_vector_type(8)));
typedef float floatx4 __attribute__((ext_vector_type(4)));

__device__ __forceinline__ float lrelu(float v) { return v >= 0.f ? v : 0.01f * v; }

// ---------------- embedding gather ----------------
__global__ void k_embed(const int* __restrict__ x, const float* __restrict__ emb,
                        float* __restrict__ h) {
    int t = blockIdx.x * 256 + threadIdx.x;
    int r = t >> 5, c4 = t & 31;
    int tok = x[r];
    ((float4*)(h + (size_t)r * FEAT))[c4] = ((const float4*)(emb + (size_t)tok * FEAT))[c4];
}

// ---------------- CSR build ----------------
__global__ void k_count(const int* __restrict__ dst, int* __restrict__ cnt) {
    int e = blockIdx.x * 256 + threadIdx.x;
    atomicAdd(&cnt[dst[e]], 1);
}

__global__ void k_partial(const int* __restrict__ cnt, int* __restrict__ part) {
    __shared__ int sm[256];
    int t = threadIdx.x;
    sm[t] = cnt[blockIdx.x * 256 + t];
    __syncthreads();
    for (int s = 128; s > 0; s >>= 1) {
        if (t < s) sm[t] += sm[t + s];
        __syncthreads();
    }
    if (t == 0) part[blockIdx.x] = sm[0];
}

__global__ void k_scanpart(const int* __restrict__ part, int* __restrict__ pscan, int nb) {
    __shared__ int sm[512];
    int t = threadIdx.x;
    int v = (t < nb) ? part[t] : 0;
    sm[t] = v;
    __syncthreads();
    for (int s = 1; s < 512; s <<= 1) {
        int add = (t >= s) ? sm[t - s] : 0;
        __syncthreads();
        sm[t] += add;
        __syncthreads();
    }
    if (t < nb) pscan[t] = sm[t] - v;   // exclusive
}

// offsets + dinv fused
__global__ void k_offsets(const int* __restrict__ cnt, const int* __restrict__ pscan,
                          int* __restrict__ offs, float* __restrict__ dinv) {
    __shared__ int sm[256];
    int t = threadIdx.x, g = blockIdx.x * 256 + t;
    int v = cnt[g];
    sm[t] = v;
    __syncthreads();
    for (int s = 1; s < 256; s <<= 1) {
        int add = (t >= s) ? sm[t - s] : 0;
        __syncthreads();
        sm[t] += add;
        __syncthreads();
    }
    offs[g] = pscan[blockIdx.x] + sm[t] - v;
    dinv[g] = rsqrtf((float)(v + 1));  // +1 self loop
}

__global__ void k_fill(const int* __restrict__ src, const int* __restrict__ dst,
                       const int* __restrict__ offs, int* __restrict__ fill,
                       const float* __restrict__ dinv,
                       int* __restrict__ csr, float* __restrict__ csrw) {
    int e = blockIdx.x * 256 + threadIdx.x;
    int d = dst[e];
    int s = src[e];
    int pos = offs[d] + atomicAdd(&fill[d], 1);
    csr[pos] = s;
    csrw[pos] = dinv[s];
}

// ---------------- weight transpose + fp16 hi/lo split, PACKED MFMA-fragment layout -------
// Packed: element index = ((ntile*(K/32) + kblk)*64 + lane)*8 + j
//   col = ntile*16 + (lane&15), k = kblk*32 + (lane>>4)*8 + j.
#define OFF_GCN 0                 // 5 x K=128 N=128
#define OFF_P0  81920             // combined mw0: K=128 N=512
#define OFF_M1  147456            // mw1: K=256 N=128
#define OFF_M2  180224            // mw2: K=128 N=128
#define OFF_M3  196608            // mw3: K=128 N=64
#define OFF_M4  204800            // mw4: K=64  N=64
#define TS_TOTAL 208896

__global__ void k_tsplit_all(const float* __restrict__ gw, const float* __restrict__ mw0,
                             const float* __restrict__ mw1, const float* __restrict__ mw2,
                             const float* __restrict__ mw3, const float* __restrict__ mw4,
                             _Float16* __restrict__ hi, _Float16* __restrict__ lo) {
    int idx = blockIdx.x * 256 + threadIdx.x;
    const float* src;
    int K, N, rel;
    bool p0 = false;
    if (idx < OFF_P0) {
        int L = (idx - OFF_GCN) >> 14; rel = (idx - OFF_GCN) & 16383;
        src = gw + L * 16384; K = 128; N = 128;
    } else if (idx < OFF_M1) {
        rel = idx - OFF_P0; src = mw0; K = 128; N = 512; p0 = true;
    } else if (idx < OFF_M2) {
        rel = idx - OFF_M1;  src = mw1; K = 256; N = 128;
    } else if (idx < OFF_M3) {
        rel = idx - OFF_M2;  src = mw2; K = 128; N = 128;
    } else if (idx < OFF_M4) {
        rel = idx - OFF_M3;  src = mw3; K = 128; N = 64;
    } else {
        rel = idx - OFF_M4;  src = mw4; K = 64;  N = 64;
    }
    int kblks = K >> 5;
    int j = rel & 7;
    int lane = (rel >> 3) & 63;
    int t2 = rel >> 9;
    int kblk = t2 % kblks;
    int ntile = t2 / kblks;
    int col = ntile * 16 + (lane & 15);
    int k = kblk * 32 + ((lane >> 4) << 3) + j;
    float f;
    if (p0) {
        f = (col < 256) ? src[k * 256 + col] : src[(k + 128) * 256 + (col - 256)];
    } else {
        f = src[k * N + col];
    }
    _Float16 h = (_Float16)f;
    hi[idx] = h;
    lo[idx] = (_Float16)(f - (float)h);
}

// ---------------- split-fp16 MFMA GEMM ----------------
// B pre-packed in fragment order (hi/lo). 3-product Markidis split, fp32 accumulate.
// Block = 256 thr = 4 waves; wave owns 32 rows x NT_N*16 cols. No LDS.
template <int NT_N, bool LEAKY, bool BIAS, bool P0SPLIT, bool FUSEA>
__launch_bounds__(256, 2)
__global__ void hgemm(const float* __restrict__ A,
                      const float* __restrict__ FA, const float* __restrict__ FB,
                      const _Float16* __restrict__ Bh, const _Float16* __restrict__ Bl,
                      const float* __restrict__ bias,
                      float* __restrict__ C, float* __restrict__ C2,
                      int N, int K) {
    const int KB = K >> 5;
    const int lane = threadIdx.x & 63;
    const int wid = threadIdx.x >> 6;
    const int lm = lane & 15, lq = lane >> 4;
    const int m0 = blockIdx.x * 128 + wid * 32;
    const int n0t = blockIdx.y * NT_N;

    const float* arow[2];
    const float* brow[2];
#pragma unroll
    for (int mt = 0; mt < 2; mt++) {
        int row = m0 + mt * 16 + lm;
        if (FUSEA) {
            int b = row / (NQ * NQ);
            int rr = row - b * (NQ * NQ);
            int i = rr / NQ;
            int j = rr - i * NQ;
            arow[mt] = FA + (size_t)(b * NQ + i) * 256;
            brow[mt] = FB + (size_t)(b * NQ + j) * 256;
        } else {
            arow[mt] = A + (size_t)row * K;
        }
    }

    floatx4 acc[2][NT_N];
#pragma unroll
    for (int mt = 0; mt < 2; mt++)
#pragma unroll
        for (int nt = 0; nt < NT_N; nt++) acc[mt][nt] = (floatx4)0.f;

    for (int kb = 0; kb < KB; kb++) {
        const int k0 = kb * 32 + lq * 8;
        half8 ahi[2], alo[2];
#pragma unroll
        for (int mt = 0; mt < 2; mt++) {
            floatx4 av0, av1;
            if (FUSEA) {
                floatx4 fa0 = *(const floatx4*)(arow[mt] + k0);
                floatx4 fa1 = *(const floatx4*)(arow[mt] + k0 + 4);
                floatx4 fb0 = *(const floatx4*)(brow[mt] + k0);
                floatx4 fb1 = *(const floatx4*)(brow[mt] + k0 + 4);
#pragma unroll
                for (int q = 0; q < 4; q++) {
                    av0[q] = lrelu(fa0[q] + fb0[q]);
                    av1[q] = lrelu(fa1[q] + fb1[q]);
                }
            } else {
                av0 = *(const floatx4*)(arow[mt] + k0);
                av1 = *(const floatx4*)(arow[mt] + k0 + 4);
            }
#pragma unroll
            for (int q = 0; q < 4; q++) {
                _Float16 h0 = (_Float16)av0[q];
                ahi[mt][q] = h0;
                alo[mt][q] = (_Float16)(av0[q] - (float)h0);
                _Float16 h1 = (_Float16)av1[q];
                ahi[mt][4 + q] = h1;
                alo[mt][4 + q] = (_Float16)(av1[q] - (float)h1);
            }
        }
#pragma unroll
        for (int nt = 0; nt < NT_N; nt++) {
            size_t boff = (((size_t)(n0t + nt) * KB + kb) * 64 + lane) * 8;
            half8 bhi = *(const half8*)(Bh + boff);
            half8 blo = *(const half8*)(Bl + boff);
#pragma unroll
            for (int mt = 0; mt < 2; mt++) {
                acc[mt][nt] = __builtin_amdgcn_mfma_f32_16x16x32_f16(ahi[mt], bhi, acc[mt][nt], 0, 0, 0);
                acc[mt][nt] = __builtin_amdgcn_mfma_f32_16x16x32_f16(ahi[mt], blo, acc[mt][nt], 0, 0, 0);
                acc[mt][nt] = __builtin_amdgcn_mfma_f32_16x16x32_f16(alo[mt], bhi, acc[mt][nt], 0, 0, 0);
            }
        }
    }

    // epilogue: C/D layout col=lane&15, row=(lane>>4)*4+reg
#pragma unroll
    for (int nt = 0; nt < NT_N; nt++) {
        int col = (n0t + nt) * 16 + lm;
        float bv = (BIAS || P0SPLIT) ? bias[col < 256 ? col : 0] : 0.f;
#pragma unroll
        for (int mt = 0; mt < 2; mt++) {
#pragma unroll
            for (int r = 0; r < 4; r++) {
                int row = m0 + mt * 16 + lq * 4 + r;
                float val = acc[mt][nt][r];
                if (P0SPLIT) {
                    if (col < 256) C[(size_t)row * 256 + col] = val + bv;
                    else C2[(size_t)row * 256 + col - 256] = val;
                } else {
                    if (BIAS) val += bv;
                    if (LEAKY) val = lrelu(val);
                    C[(size_t)row * N + col] = val;
                }
            }
        }
    }
}

// ---------------- GCN aggregation + bias + leaky + residual (ping-pong) ----------------
// half-wave per node (32 lanes x float4 = 1 row); clamp-masked unroll-4.
__global__ void k_agg(const float* __restrict__ hw, const float* __restrict__ hold,
                      const int* __restrict__ csr, const float* __restrict__ csrw,
                      const int* __restrict__ offs, const int* __restrict__ cnt,
                      const float* __restrict__ dinv, const float* __restrict__ bias,
                      float* __restrict__ hnew) {
    int tid = threadIdx.x;
    int sl = tid & 31;
    int node = blockIdx.x * 8 + (tid >> 5);
    float di = dinv[node];
    int off = offs[node], deg = cnt[node];
    float s2 = di * di;
    float4 v = ((const float4*)(hw + (size_t)node * FEAT))[sl];
    float ax = v.x * s2, ay = v.y * s2, az = v.z * s2, aw = v.w * s2;
    for (int e = 0; e < deg; e += 4) {
        int e0 = e, e1 = min(e + 1, deg - 1), e2 = min(e + 2, deg - 1), e3 = min(e + 3, deg - 1);
        int s0i = csr[off + e0], s1i = csr[off + e1], s2i = csr[off + e2], s3i = csr[off + e3];
        float w0 = csrw[off + e0] * di;
        float w1 = (e + 1 < deg) ? csrw[off + e1] * di : 0.f;
        float w2 = (e + 2 < deg) ? csrw[off + e2] * di : 0.f;
        float w3 = (e + 3 < deg) ? csrw[off + e3] * di : 0.f;
        float4 u0 = ((const float4*)(hw + (size_t)s0i * FEAT))[sl];
        float4 u1 = ((const float4*)(hw + (size_t)s1i * FEAT))[sl];
        float4 u2 = ((const float4*)(hw + (size_t)s2i * FEAT))[sl];
        float4 u3 = ((const float4*)(hw + (size_t)s3i * FEAT))[sl];
        ax += u0.x * w0 + u1.x * w1 + u2.x * w2 + u3.x * w3;
        ay += u0.y * w0 + u1.y * w1 + u2.y * w2 + u3.y * w3;
        az += u0.z * w0 + u1.z * w1 + u2.z * w2 + u3.z * w3;
        aw += u0.w * w0 + u1.w * w1 + u2.w * w2 + u3.w * w3;
    }
    float4 bv = ((const float4*)bias)[sl];
    ax = lrelu(ax + bv.x); ay = lrelu(ay + bv.y);
    az = lrelu(az + bv.z); aw = lrelu(aw + bv.w);
    float4 ho = ((const float4*)(hold + (size_t)node * FEAT))[sl];
    ((float4*)(hnew + (size_t)node * FEAT))[sl] = make_float4(ax + ho.x, ay + ho.y, az + ho.z, aw + ho.w);
}

// ---------------- selective final agg (layer 4): S0 rows only -> hq, no leaky ----------------
// S0 is statically known: node = b*(NQ*NLAY) + i, q = b*NQ + i.
__global__ void k_aggq(const float* __restrict__ hw, const float* __restrict__ h,
                       const int* __restrict__ csr, const float* __restrict__ csrw,
                       const int* __restrict__ offs, const int* __restrict__ cnt,
                       const float* __restrict__ dinv, const float* __restrict__ gbias,
                       float* __restrict__ hq) {
    int tid = threadIdx.x;
    int sl = tid & 31;
    int q = blockIdx.x * 8 + (tid >> 5);   // 0..2559
    int b = q / NQ, i = q - b * NQ;
    int node = b * (NQ * NLAY) + i;
    float di = dinv[node];
    int off = offs[node], deg = cnt[node];
    float s2 = di * di;
    float4 v = ((const float4*)(hw + (size_t)node * FEAT))[sl];
    float ax = v.x * s2, ay = v.y * s2, az = v.z * s2, aw = v.w * s2;
    for (int e = 0; e < deg; e += 4) {
        int e0 = e, e1 = min(e + 1, deg - 1), e2 = min(e + 2, deg - 1), e3 = min(e + 3, deg - 1);
        int s0i = csr[off + e0], s1i = csr[off + e1], s2i = csr[off + e2], s3i = csr[off + e3];
        float w0 = csrw[off + e0] * di;
        float w1 = (e + 1 < deg) ? csrw[off + e1] * di : 0.f;
        float w2 = (e + 2 < deg) ? csrw[off + e2] * di : 0.f;
        float w3 = (e + 3 < deg) ? csrw[off + e3] * di : 0.f;
        float4 u0 = ((const float4*)(hw + (size_t)s0i * FEAT))[sl];
        float4 u1 = ((const float4*)(hw + (size_t)s1i * FEAT))[sl];
        float4 u2 = ((const float4*)(hw + (size_t)s2i * FEAT))[sl];
        float4 u3 = ((const float4*)(hw + (size_t)s3i * FEAT))[sl];
        ax += u0.x * w0 + u1.x * w1 + u2.x * w2 + u3.x * w3;
        ay += u0.y * w0 + u1.y * w1 + u2.y * w2 + u3.y * w3;
        az += u0.z * w0 + u1.z * w1 + u2.z * w2 + u3.z * w3;
        aw += u0.w * w0 + u1.w * w1 + u2.w * w2 + u3.w * w3;
    }
    float4 bv = ((const float4*)gbias)[sl];
    float4 ho = ((const float4*)(h + (size_t)node * FEAT))[sl];
    ((float4*)(hq + (size_t)q * FEAT))[sl] =
        make_float4(ax + bv.x + ho.x, ay + bv.y + ho.y, az + bv.z + ho.z, aw + bv.w + ho.w);
}

// ---------------- last layer + symmetrize, one block per batch ----------------
__global__ void k_lastsym(const float* __restrict__ X4, const float* __restrict__ mw5,
                          const float* __restrict__ mb5, float* __restrict__ out) {
    __shared__ float w[64];
    __shared__ float sm[NQ * NQ];
    int t = threadIdx.x;
    if (t < 64) w[t] = mw5[t];
    __syncthreads();
    int b = blockIdx.x;
    for (int p = t; p < NQ * NQ; p += 256) {
        const float4* row = (const float4*)(X4 + (size_t)(b * NQ * NQ + p) * 64);
        float s = 0.f;
#pragma unroll
        for (int k4 = 0; k4 < 16; k4++) {
            float4 v = row[k4];
            s += v.x * w[k4 * 4] + v.y * w[k4 * 4 + 1] + v.z * w[k4 * 4 + 2] + v.w * w[k4 * 4 + 3];
        }
        sm[p] = s + mb5[0];
    }
    __syncthreads();
    for (int r = t; r < NQ * NQ; r += 256) {
        int i = r / NQ, j = r % NQ;
        out[(size_t)b * NQ * NQ + r] = 0.5f * (sm[r] + sm[j * NQ + i]);
    }
}

extern "C" void kernel_launch(void* const* d_in, const int* in_sizes, int n_in,
                              void* d_out, int out_size, void* d_ws, size_t ws_size,
                              hipStream_t stream) {
    const int* x = (const int*)d_in[0];
    const int* ei = (const int*)d_in[1];
    const int* e_src = ei;
    const int* e_dst = ei + NE;
    const float* emb = (const float*)d_in[2];
    const float* gw = (const float*)d_in[3];   // [5,128,128]
    const float* gb = (const float*)d_in[4];   // [5,128]
    const float* mw0 = (const float*)d_in[5];
    const float* mb0 = (const float*)d_in[6];
    const float* mw1 = (const float*)d_in[7];
    const float* mb1 = (const float*)d_in[8];
    const float* mw2 = (const float*)d_in[9];
    const float* mb2 = (const float*)d_in[10];
    const float* mw3 = (const float*)d_in[11];
    const float* mb3 = (const float*)d_in[12];
    const float* mw4 = (const float*)d_in[13];
    const float* mb4 = (const float*)d_in[14];
    const float* mw5 = (const float*)d_in[15];
    const float* mb5 = (const float*)d_in[16];
    float* out = (float*)d_out;

    float* wsf = (float*)d_ws;
    size_t o = 0;
    const size_t HSZ = (size_t)NN * FEAT;             // 16,711,680
    float* hA = wsf + o; o += HSZ;
    float* hw = wsf + o; o += HSZ;
    float* hB = wsf + o; o += HSZ;
    int* cnt  = (int*)(wsf + o); o += NN;
    int* fill = (int*)(wsf + o); o += NN;   // adjacent to cnt -> single memset
    int* offs = (int*)(wsf + o); o += NN;
    int* csr  = (int*)(wsf + o); o += NE + 8;   // +8: clamped-index slop
    float* csrw = wsf + o; o += NE + 8;
    float* dinv = wsf + o; o += NN;
    int* part  = (int*)(wsf + o); o += 512;
    int* pscan = (int*)(wsf + o); o += 512;
    float* hq = wsf + o; o += (size_t)BATCH * NQ * FEAT;     // 327,680
    float* Abuf = wsf + o; o += (size_t)BATCH * NQ * 256;    // 655,360
    float* Bbuf = wsf + o; o += (size_t)BATCH * NQ * 256;    // 655,360
    _Float16* bt_hi = (_Float16*)(wsf + o); o += (TS_TOTAL + 2) / 2;
    _Float16* bt_lo = (_Float16*)(wsf + o); o += (TS_TOTAL + 2) / 2;
    // pair-phase aliases (buffers dead by then; hA holds h4 until aggq, hB/hw free after)
    float* X1 = hw;                         // 51200*128 (hw dead after aggq)
    float* X2 = hw + (size_t)NPAIR * 128;   // 51200*128
    float* X3 = hB;                         // 51200*64
    float* X4 = hB + (size_t)NPAIR * 64;    // 51200*64

    const int NB = NN / 256;  // 510

    // --- weight transpose+split+pack ---
    k_tsplit_all<<<TS_TOTAL / 256, 256, 0, stream>>>(gw, mw0, mw1, mw2, mw3, mw4, bt_hi, bt_lo);

    // --- CSR build ---
    hipMemsetAsync(cnt, 0, 2 * NN * sizeof(int), stream);  // cnt + fill
    k_count<<<NE / 256, 256, 0, stream>>>(e_dst, cnt);
    k_partial<<<NB, 256, 0, stream>>>(cnt, part);
    k_scanpart<<<1, 512, 0, stream>>>(part, pscan, NB);
    k_offsets<<<NB, 256, 0, stream>>>(cnt, pscan, offs, dinv);
    k_fill<<<NE / 256, 256, 0, stream>>>(e_src, e_dst, offs, fill, dinv, csr, csrw);

    // --- embedding -> h0 ---
    k_embed<<<(NN * 32) / 256, 256, 0, stream>>>(x, emb, hA);

    // --- GCN layers 0..3: gemm(hin->hw) + agg(hw,hin->hout), ping-pong ---
    float* hin = hA;
    float* hout = hB;
    for (int L = 0; L < 4; L++) {
        hgemm<8, false, false, false, false><<<dim3(NN / 128, 1), 256, 0, stream>>>(
            hin, nullptr, nullptr, bt_hi + OFF_GCN + L * 16384, bt_lo + OFF_GCN + L * 16384,
            nullptr, hw, nullptr, FEAT, FEAT);
        k_agg<<<NN / 8, 256, 0, stream>>>(hw, hin, csr, csrw, offs, cnt, dinv,
                                          gb + (size_t)L * FEAT, hout);
        float* t = hin; hin = hout; hout = t;
    }
    // h4 in hin (== hA after 4 swaps)

    // --- layer 4: full gemm, selective agg (only the 2560 pair-phase rows) -> hq ---
    hgemm<8, false, false, false, false><<<dim3(NN / 128, 1), 256, 0, stream>>>(
        hin, nullptr, nullptr, bt_hi + OFF_GCN + 4 * 16384, bt_lo + OFF_GCN + 4 * 16384,
        nullptr, hw, nullptr, FEAT, FEAT);
    k_aggq<<<(BATCH * NQ) / 8, 256, 0, stream>>>(hw, hin, csr, csrw, offs, cnt, dinv,
                                                 gb + 4 * (size_t)FEAT, hq);

    // --- pair MLP ---
    // combined P0: Abuf = hq@mw0_top + mb0 ; Bbuf = hq@mw0_bot   (M=2560, K=128, N=512)
    hgemm<8, false, false, true, false><<<dim3(20, 4), 256, 0, stream>>>(
        hq, nullptr, nullptr, bt_hi + OFF_P0, bt_lo + OFF_P0, mb0, Abuf, Bbuf, 512, 128);
    // L1 fused pair0: A[p,:] = lrelu(Abuf[b,i,:] + Bbuf[b,j,:]) ; [51200,256]@[256,128]
    hgemm<8, true, true, false, true><<<dim3(NPAIR / 128, 1), 256, 0, stream>>>(
        nullptr, Abuf, Bbuf, bt_hi + OFF_M1, bt_lo + OFF_M1, mb1, X1, nullptr, 128, 256);
    // L2: [51200,128] @ [128,128]
    hgemm<8, true, true, false, false><<<dim3(NPAIR / 128, 1), 256, 0, stream>>>(
        X1, nullptr, nullptr, bt_hi + OFF_M2, bt_lo + OFF_M2, mb2, X2, nullptr, 128, 128);
    // L3: [51200,128] @ [128,64]
    hgemm<4, true, true, false, false><<<dim3(NPAIR / 128, 1), 256, 0, stream>>>(
        X2, nullptr, nullptr, bt_hi + OFF_M3, bt_lo + OFF_M3, mb3, X3, nullptr, 64, 128);
    // L4: [51200,64] @ [64,64]
    hgemm<4, true, true, false, false><<<dim3(NPAIR / 128, 1), 256, 0, stream>>>(
        X3, nullptr, nullptr, bt_hi + OFF_M4, bt_lo + OFF_M4, mb4, X4, nullptr, 64, 64);
    // L5 + symmetrize
    k_lastsym<<<BATCH, 256, 0, stream>>>(X4, mw5, mb5, out);
}

// Round 7
// 639.841 us; speedup vs baseline: 1.1569x; 1.0381x over previous
//
#include <hip/hip_runtime.h>
#include <hip/hip_bf16.h>

#define NQ 20
#define NLAY 51            // N_LAYER+1
#define FEAT 128
#define BATCH 128
#define NN (BATCH * NQ * NLAY)   // 130560
#define NE 524288
#define NPAIR (BATCH * NQ * NQ)  // 51200

typedef _Float16 half8 __attribute__((ext_vector_type(8)));
typedef float floatx4 __attribute__((ext_vector_type(4)));

__device__ __forceinline__ float lrelu(float v) { return v >= 0.f ? v : 0.01f * v; }

// ---------------- CSR build ----------------
__global__ void k_count(const int* __restrict__ dst, int* __restrict__ cnt) {
    int e = blockIdx.x * 256 + threadIdx.x;
    atomicAdd(&cnt[dst[e]], 1);
}

__global__ void k_partial(const int* __restrict__ cnt, int* __restrict__ part) {
    __shared__ int sm[256];
    int t = threadIdx.x;
    sm[t] = cnt[blockIdx.x * 256 + t];
    __syncthreads();
    for (int s = 128; s > 0; s >>= 1) {
        if (t < s) sm[t] += sm[t + s];
        __syncthreads();
    }
    if (t == 0) part[blockIdx.x] = sm[0];
}

__global__ void k_scanpart(const int* __restrict__ part, int* __restrict__ pscan, int nb) {
    __shared__ int sm[512];
    int t = threadIdx.x;
    int v = (t < nb) ? part[t] : 0;
    sm[t] = v;
    __syncthreads();
    for (int s = 1; s < 512; s <<= 1) {
        int add = (t >= s) ? sm[t - s] : 0;
        __syncthreads();
        sm[t] += add;
        __syncthreads();
    }
    if (t < nb) pscan[t] = sm[t] - v;   // exclusive
}

// offsets + dinv + packed meta {off, deg, dinv_bits, x[node]}
__global__ void k_offsets(const int* __restrict__ cnt, const int* __restrict__ pscan,
                          const int* __restrict__ x,
                          int* __restrict__ offs, float* __restrict__ dinv,
                          int4* __restrict__ meta) {
    __shared__ int sm[256];
    int t = threadIdx.x, g = blockIdx.x * 256 + t;
    int v = cnt[g];
    sm[t] = v;
    __syncthreads();
    for (int s = 1; s < 256; s <<= 1) {
        int add = (t >= s) ? sm[t - s] : 0;
        __syncthreads();
        sm[t] += add;
        __syncthreads();
    }
    int off = pscan[blockIdx.x] + sm[t] - v;
    float di = rsqrtf((float)(v + 1));  // +1 self loop
    offs[g] = off;
    dinv[g] = di;
    meta[g] = make_int4(off, v, __float_as_int(di), x[g]);
}

// fill packed edges {src, dinv[src]_bits}
__global__ void k_fill(const int* __restrict__ src, const int* __restrict__ dst,
                       const int* __restrict__ offs, int* __restrict__ fill,
                       const float* __restrict__ dinv, int2* __restrict__ csre) {
    int e = blockIdx.x * 256 + threadIdx.x;
    int d = dst[e];
    int s = src[e];
    int pos = offs[d] + atomicAdd(&fill[d], 1);
    csre[pos] = make_int2(s, __float_as_int(dinv[s]));
}

// ---------------- weight transpose + fp16 hi/lo split, PACKED MFMA-fragment layout -------
// Packed: element index = ((ntile*(K/32) + kblk)*64 + lane)*8 + j
//   col = ntile*16 + (lane&15), k = kblk*32 + (lane>>4)*8 + j.
#define OFF_GCN 0                 // 5 x K=128 N=128
#define OFF_P0  81920             // combined mw0: K=128 N=512
#define OFF_M1  147456            // mw1: K=256 N=128
#define OFF_M2  180224            // mw2: K=128 N=128
#define OFF_M3  196608            // mw3: K=128 N=64
#define OFF_M4  204800            // mw4: K=64  N=64
#define TS_TOTAL 208896

__global__ void k_tsplit_all(const float* __restrict__ gw, const float* __restrict__ mw0,
                             const float* __restrict__ mw1, const float* __restrict__ mw2,
                             const float* __restrict__ mw3, const float* __restrict__ mw4,
                             _Float16* __restrict__ hi, _Float16* __restrict__ lo) {
    int idx = blockIdx.x * 256 + threadIdx.x;
    const float* src;
    int K, N, rel;
    bool p0 = false;
    if (idx < OFF_P0) {
        int L = (idx - OFF_GCN) >> 14; rel = (idx - OFF_GCN) & 16383;
        src = gw + L * 16384; K = 128; N = 128;
    } else if (idx < OFF_M1) {
        rel = idx - OFF_P0; src = mw0; K = 128; N = 512; p0 = true;
    } else if (idx < OFF_M2) {
        rel = idx - OFF_M1;  src = mw1; K = 256; N = 128;
    } else if (idx < OFF_M3) {
        rel = idx - OFF_M2;  src = mw2; K = 128; N = 128;
    } else if (idx < OFF_M4) {
        rel = idx - OFF_M3;  src = mw3; K = 128; N = 64;
    } else {
        rel = idx - OFF_M4;  src = mw4; K = 64;  N = 64;
    }
    int kblks = K >> 5;
    int j = rel & 7;
    int lane = (rel >> 3) & 63;
    int t2 = rel >> 9;
    int kblk = t2 % kblks;
    int ntile = t2 / kblks;
    int col = ntile * 16 + (lane & 15);
    int k = kblk * 32 + ((lane >> 4) << 3) + j;
    float f;
    if (p0) {
        f = (col < 256) ? src[k * 256 + col] : src[(k + 128) * 256 + (col - 256)];
    } else {
        f = src[k * N + col];
    }
    _Float16 h = (_Float16)f;
    hi[idx] = h;
    lo[idx] = (_Float16)(f - (float)h);
}

// ---------------- split-fp16 MFMA GEMM ----------------
// B pre-packed in fragment order (hi/lo). 3-product Markidis split, fp32 accumulate.
// Block = 256 thr = 4 waves; wave owns 32 rows x NT_N*16 cols. No LDS.
// GATHA: A-rows indirected through gmap (embedding-gather fusion).
template <int NT_N, bool LEAKY, bool BIAS, bool P0SPLIT, bool FUSEA, bool GATHA>
__launch_bounds__(256, 2)
__global__ void hgemm(const float* __restrict__ A,
                      const float* __restrict__ FA, const float* __restrict__ FB,
                      const _Float16* __restrict__ Bh, const _Float16* __restrict__ Bl,
                      const float* __restrict__ bias,
                      float* __restrict__ C, float* __restrict__ C2,
                      int N, int K, const int* __restrict__ gmap) {
    const int KB = K >> 5;
    const int lane = threadIdx.x & 63;
    const int wid = threadIdx.x >> 6;
    const int lm = lane & 15, lq = lane >> 4;
    const int m0 = blockIdx.x * 128 + wid * 32;
    const int n0t = blockIdx.y * NT_N;

    const float* arow[2];
    const float* brow[2];
#pragma unroll
    for (int mt = 0; mt < 2; mt++) {
        int row = m0 + mt * 16 + lm;
        if (FUSEA) {
            int b = row / (NQ * NQ);
            int rr = row - b * (NQ * NQ);
            int i = rr / NQ;
            int j = rr - i * NQ;
            arow[mt] = FA + (size_t)(b * NQ + i) * 256;
            brow[mt] = FB + (size_t)(b * NQ + j) * 256;
        } else if (GATHA) {
            arow[mt] = A + (size_t)gmap[row] * K;
        } else {
            arow[mt] = A + (size_t)row * K;
        }
    }

    floatx4 acc[2][NT_N];
#pragma unroll
    for (int mt = 0; mt < 2; mt++)
#pragma unroll
        for (int nt = 0; nt < NT_N; nt++) acc[mt][nt] = (floatx4)0.f;

    for (int kb = 0; kb < KB; kb++) {
        const int k0 = kb * 32 + lq * 8;
        half8 ahi[2], alo[2];
#pragma unroll
        for (int mt = 0; mt < 2; mt++) {
            floatx4 av0, av1;
            if (FUSEA) {
                floatx4 fa0 = *(const floatx4*)(arow[mt] + k0);
                floatx4 fa1 = *(const floatx4*)(arow[mt] + k0 + 4);
                floatx4 fb0 = *(const floatx4*)(brow[mt] + k0);
                floatx4 fb1 = *(const floatx4*)(brow[mt] + k0 + 4);
#pragma unroll
                for (int q = 0; q < 4; q++) {
                    av0[q] = lrelu(fa0[q] + fb0[q]);
                    av1[q] = lrelu(fa1[q] + fb1[q]);
                }
            } else {
                av0 = *(const floatx4*)(arow[mt] + k0);
                av1 = *(const floatx4*)(arow[mt] + k0 + 4);
            }
#pragma unroll
            for (int q = 0; q < 4; q++) {
                _Float16 h0 = (_Float16)av0[q];
                ahi[mt][q] = h0;
                alo[mt][q] = (_Float16)(av0[q] - (float)h0);
                _Float16 h1 = (_Float16)av1[q];
                ahi[mt][4 + q] = h1;
                alo[mt][4 + q] = (_Float16)(av1[q] - (float)h1);
            }
        }
#pragma unroll
        for (int nt = 0; nt < NT_N; nt++) {
            size_t boff = (((size_t)(n0t + nt) * KB + kb) * 64 + lane) * 8;
            half8 bhi = *(const half8*)(Bh + boff);
            half8 blo = *(const half8*)(Bl + boff);
#pragma unroll
            for (int mt = 0; mt < 2; mt++) {
                acc[mt][nt] = __builtin_amdgcn_mfma_f32_16x16x32_f16(ahi[mt], bhi, acc[mt][nt], 0, 0, 0);
                acc[mt][nt] = __builtin_amdgcn_mfma_f32_16x16x32_f16(ahi[mt], blo, acc[mt][nt], 0, 0, 0);
                acc[mt][nt] = __builtin_amdgcn_mfma_f32_16x16x32_f16(alo[mt], bhi, acc[mt][nt], 0, 0, 0);
            }
        }
    }

    // epilogue: C/D layout col=lane&15, row=(lane>>4)*4+reg
#pragma unroll
    for (int nt = 0; nt < NT_N; nt++) {
        int col = (n0t + nt) * 16 + lm;
        float bv = (BIAS || P0SPLIT) ? bias[col < 256 ? col : 0] : 0.f;
#pragma unroll
        for (int mt = 0; mt < 2; mt++) {
#pragma unroll
            for (int r = 0; r < 4; r++) {
                int row = m0 + mt * 16 + lq * 4 + r;
                float val = acc[mt][nt][r];
                if (P0SPLIT) {
                    if (col < 256) C[(size_t)row * 256 + col] = val + bv;
                    else C2[(size_t)row * 256 + col - 256] = val;
                } else {
                    if (BIAS) val += bv;
                    if (LEAKY) val = lrelu(val);
                    C[(size_t)row * N + col] = val;
                }
            }
        }
    }
}

// ---------------- GCN aggregation + bias + leaky + residual (ping-pong) ----------------
// half-wave per TWO nodes (32 lanes x float4 = 1 row); packed meta (1 load) + packed
// edges (1 broadcast load each); clamp-masked unroll-4 x 2 nodes = 8 gathers in flight.
// embt != null: residual row comes from embt[meta.w] (layer 0, h0 never materialized).
__global__ void k_agg(const float* __restrict__ hw, const float* __restrict__ hold,
                      const int4* __restrict__ meta, const int2* __restrict__ csre,
                      const float* __restrict__ bias, float* __restrict__ hnew,
                      const float* __restrict__ embt) {
    int tid = threadIdx.x;
    int sl = tid & 31;
    int p = blockIdx.x * 8 + (tid >> 5);
    int n0 = p * 2, n1 = n0 + 1;
    int4 m0 = meta[n0], m1 = meta[n1];
    float di0 = __int_as_float(m0.z), di1 = __int_as_float(m1.z);
    int off0 = m0.x, deg0 = m0.y;
    int off1 = m1.x, deg1 = m1.y;
    // independent early loads: self rows + residual rows
    float4 v0 = ((const float4*)(hw + (size_t)n0 * FEAT))[sl];
    float4 v1 = ((const float4*)(hw + (size_t)n1 * FEAT))[sl];
    float4 ho0, ho1;
    if (embt) {
        ho0 = ((const float4*)(embt + (size_t)m0.w * FEAT))[sl];
        ho1 = ((const float4*)(embt + (size_t)m1.w * FEAT))[sl];
    } else {
        ho0 = ((const float4*)(hold + (size_t)n0 * FEAT))[sl];
        ho1 = ((const float4*)(hold + (size_t)n1 * FEAT))[sl];
    }
    float s20 = di0 * di0, s21 = di1 * di1;
    float a0x = v0.x * s20, a0y = v0.y * s20, a0z = v0.z * s20, a0w = v0.w * s20;
    float a1x = v1.x * s21, a1y = v1.y * s21, a1z = v1.z * s21, a1w = v1.w * s21;
    int d0c = max(deg0 - 1, 0), d1c = max(deg1 - 1, 0);
    int dm = max(deg0, deg1);
    for (int e = 0; e < dm; e += 4) {
        int2 e00 = csre[off0 + min(e,     d0c)];
        int2 e01 = csre[off0 + min(e + 1, d0c)];
        int2 e02 = csre[off0 + min(e + 2, d0c)];
        int2 e03 = csre[off0 + min(e + 3, d0c)];
        int2 e10 = csre[off1 + min(e,     d1c)];
        int2 e11 = csre[off1 + min(e + 1, d1c)];
        int2 e12 = csre[off1 + min(e + 2, d1c)];
        int2 e13 = csre[off1 + min(e + 3, d1c)];
        float4 u00 = ((const float4*)(hw + (size_t)e00.x * FEAT))[sl];
        float4 u01 = ((const float4*)(hw + (size_t)e01.x * FEAT))[sl];
        float4 u02 = ((const float4*)(hw + (size_t)e02.x * FEAT))[sl];
        float4 u03 = ((const float4*)(hw + (size_t)e03.x * FEAT))[sl];
        float4 u10 = ((const float4*)(hw + (size_t)e10.x * FEAT))[sl];
        float4 u11 = ((const float4*)(hw + (size_t)e11.x * FEAT))[sl];
        float4 u12 = ((const float4*)(hw + (size_t)e12.x * FEAT))[sl];
        float4 u13 = ((const float4*)(hw + (size_t)e13.x * FEAT))[sl];
        float w00 = (e     < deg0) ? __int_as_float(e00.y) * di0 : 0.f;
        float w01 = (e + 1 < deg0) ? __int_as_float(e01.y) * di0 : 0.f;
        float w02 = (e + 2 < deg0) ? __int_as_float(e02.y) * di0 : 0.f;
        float w03 = (e + 3 < deg0) ? __int_as_float(e03.y) * di0 : 0.f;
        float w10 = (e     < deg1) ? __int_as_float(e10.y) * di1 : 0.f;
        float w11 = (e + 1 < deg1) ? __int_as_float(e11.y) * di1 : 0.f;
        float w12 = (e + 2 < deg1) ? __int_as_float(e12.y) * di1 : 0.f;
        float w13 = (e + 3 < deg1) ? __int_as_float(e13.y) * di1 : 0.f;
        a0x += u00.x * w00 + u01.x * w01 + u02.x * w02 + u03.x * w03;
        a0y += u00.y * w00 + u01.y * w01 + u02.y * w02 + u03.y * w03;
        a0z += u00.z * w00 + u01.z * w01 + u02.z * w02 + u03.z * w03;
        a0w += u00.w * w00 + u01.w * w01 + u02.w * w02 + u03.w * w03;
        a1x += u10.x * w10 + u11.x * w11 + u12.x * w12 + u13.x * w13;
        a1y += u10.y * w10 + u11.y * w11 + u12.y * w12 + u13.y * w13;
        a1z += u10.z * w10 + u11.z * w11 + u12.z * w12 + u13.z * w13;
        a1w += u10.w * w10 + u11.w * w11 + u12.w * w12 + u13.w * w13;
    }
    float4 bv = ((const float4*)bias)[sl];
    float4 r0, r1;
    r0.x = lrelu(a0x + bv.x) + ho0.x;
    r0.y = lrelu(a0y + bv.y) + ho0.y;
    r0.z = lrelu(a0z + bv.z) + ho0.z;
    r0.w = lrelu(a0w + bv.w) + ho0.w;
    r1.x = lrelu(a1x + bv.x) + ho1.x;
    r1.y = lrelu(a1y + bv.y) + ho1.y;
    r1.z = lrelu(a1z + bv.z) + ho1.z;
    r1.w = lrelu(a1w + bv.w) + ho1.w;
    ((float4*)(hnew + (size_t)n0 * FEAT))[sl] = r0;
    ((float4*)(hnew + (size_t)n1 * FEAT))[sl] = r1;
}

// ---------------- selective final agg (layer 4): S0 rows only -> hq, no leaky ----------------
__global__ void k_aggq(const float* __restrict__ hw, const float* __restrict__ h,
                       const int4* __restrict__ meta, const int2* __restrict__ csre,
                       const float* __restrict__ gbias, float* __restrict__ hq) {
    int tid = threadIdx.x;
    int sl = tid & 31;
    int q = blockIdx.x * 8 + (tid >> 5);   // 0..2559
    int b = q / NQ, i = q - b * NQ;
    int node = b * (NQ * NLAY) + i;
    int4 m = meta[node];
    float di = __int_as_float(m.z);
    int off = m.x, deg = m.y;
    float s2 = di * di;
    float4 v = ((const float4*)(hw + (size_t)node * FEAT))[sl];
    float ax = v.x * s2, ay = v.y * s2, az = v.z * s2, aw = v.w * s2;
    int dc = max(deg - 1, 0);
    for (int e = 0; e < deg; e += 4) {
        int2 e0 = csre[off + min(e,     dc)];
        int2 e1 = csre[off + min(e + 1, dc)];
        int2 e2 = csre[off + min(e + 2, dc)];
        int2 e3 = csre[off + min(e + 3, dc)];
        float4 u0 = ((const float4*)(hw + (size_t)e0.x * FEAT))[sl];
        float4 u1 = ((const float4*)(hw + (size_t)e1.x * FEAT))[sl];
        float4 u2 = ((const float4*)(hw + (size_t)e2.x * FEAT))[sl];
        float4 u3 = ((const float4*)(hw + (size_t)e3.x * FEAT))[sl];
        float w0 = (e     < deg) ? __int_as_float(e0.y) * di : 0.f;
        float w1 = (e + 1 < deg) ? __int_as_float(e1.y) * di : 0.f;
        float w2 = (e + 2 < deg) ? __int_as_float(e2.y) * di : 0.f;
        float w3 = (e + 3 < deg) ? __int_as_float(e3.y) * di : 0.f;
        ax += u0.x * w0 + u1.x * w1 + u2.x * w2 + u3.x * w3;
        ay += u0.y * w0 + u1.y * w1 + u2.y * w2 + u3.y * w3;
        az += u0.z * w0 + u1.z * w1 + u2.z * w2 + u3.z * w3;
        aw += u0.w * w0 + u1.w * w1 + u2.w * w2 + u3.w * w3;
    }
    float4 bv = ((const float4*)gbias)[sl];
    float4 ho = ((const float4*)(h + (size_t)node * FEAT))[sl];
    ((float4*)(hq + (size_t)q * FEAT))[sl] =
        make_float4(ax + bv.x + ho.x, ay + bv.y + ho.y, az + bv.z + ho.z, aw + bv.w + ho.w);
}

// ---------------- last layer + symmetrize, one block per batch ----------------
__global__ void k_lastsym(const float* __restrict__ X4, const float* __restrict__ mw5,
                          const float* __restrict__ mb5, float* __restrict__ out) {
    __shared__ float w[64];
    __shared__ float sm[NQ * NQ];
    int t = threadIdx.x;
    if (t < 64) w[t] = mw5[t];
    __syncthreads();
    int b = blockIdx.x;
    for (int p = t; p < NQ * NQ; p += 256) {
        const float4* row = (const float4*)(X4 + (size_t)(b * NQ * NQ + p) * 64);
        float s = 0.f;
#pragma unroll
        for (int k4 = 0; k4 < 16; k4++) {
            float4 v = row[k4];
            s += v.x * w[k4 * 4] + v.y * w[k4 * 4 + 1] + v.z * w[k4 * 4 + 2] + v.w * w[k4 * 4 + 3];
        }
        sm[p] = s + mb5[0];
    }
    __syncthreads();
    for (int r = t; r < NQ * NQ; r += 256) {
        int i = r / NQ, j = r % NQ;
        out[(size_t)b * NQ * NQ + r] = 0.5f * (sm[r] + sm[j * NQ + i]);
    }
}

extern "C" void kernel_launch(void* const* d_in, const int* in_sizes, int n_in,
                              void* d_out, int out_size, void* d_ws, size_t ws_size,
                              hipStream_t stream) {
    const int* x = (const int*)d_in[0];
    const int* ei = (const int*)d_in[1];
    const int* e_src = ei;
    const int* e_dst = ei + NE;
    const float* emb = (const float*)d_in[2];
    const float* gw = (const float*)d_in[3];   // [5,128,128]
    const float* gb = (const float*)d_in[4];   // [5,128]
    const float* mw0 = (const float*)d_in[5];
    const float* mb0 = (const float*)d_in[6];
    const float* mw1 = (const float*)d_in[7];
    const float* mb1 = (const float*)d_in[8];
    const float* mw2 = (const float*)d_in[9];
    const float* mb2 = (const float*)d_in[10];
    const float* mw3 = (const float*)d_in[11];
    const float* mb3 = (const float*)d_in[12];
    const float* mw4 = (const float*)d_in[13];
    const float* mb4 = (const float*)d_in[14];
    const float* mw5 = (const float*)d_in[15];
    const float* mb5 = (const float*)d_in[16];
    float* out = (float*)d_out;

    float* wsf = (float*)d_ws;
    size_t o = 0;
    const size_t HSZ = (size_t)NN * FEAT;             // 16,711,680
    float* hA = wsf + o; o += HSZ;
    float* hw = wsf + o; o += HSZ;
    float* hB = wsf + o; o += HSZ;
    int* cnt  = (int*)(wsf + o); o += NN;
    int* fill = (int*)(wsf + o); o += NN;   // adjacent to cnt -> single memset
    int* offs = (int*)(wsf + o); o += NN;
    float* dinv = wsf + o; o += NN;
    int4* meta = (int4*)(wsf + o); o += 4 * (size_t)NN;
    int2* csre = (int2*)(wsf + o); o += 2 * (size_t)(NE + 8);  // +8 slop for deg-0 clamp
    int* part  = (int*)(wsf + o); o += 512;
    int* pscan = (int*)(wsf + o); o += 512;
    float* hq = wsf + o; o += (size_t)BATCH * NQ * FEAT;     // 327,680
    float* Abuf = wsf + o; o += (size_t)BATCH * NQ * 256;    // 655,360
    float* Bbuf = wsf + o; o += (size_t)BATCH * NQ * 256;    // 655,360
    _Float16* bt_hi = (_Float16*)(wsf + o); o += (TS_TOTAL + 2) / 2;
    _Float16* bt_lo = (_Float16*)(wsf + o); o += (TS_TOTAL + 2) / 2;
    // pair-phase aliases (buffers dead by then; hA holds h4 until aggq, hB/hw free after)
    float* X1 = hw;                         // 51200*128 (hw dead after aggq)
    float* X2 = hw + (size_t)NPAIR * 128;   // 51200*128
    float* X3 = hB;                         // 51200*64
    float* X4 = hB + (size_t)NPAIR * 64;    // 51200*64

    const int NB = NN / 256;  // 510

    // --- weight transpose+split+pack ---
    k_tsplit_all<<<TS_TOTAL / 256, 256, 0, stream>>>(gw, mw0, mw1, mw2, mw3, mw4, bt_hi, bt_lo);

    // --- CSR build ---
    hipMemsetAsync(cnt, 0, 2 * NN * sizeof(int), stream);  // cnt + fill
    hipMemsetAsync(csre + NE, 0, 8 * sizeof(int2), stream);  // slop: safe node 0, weight 0
    k_count<<<NE / 256, 256, 0, stream>>>(e_dst, cnt);
    k_partial<<<NB, 256, 0, stream>>>(cnt, part);
    k_scanpart<<<1, 512, 0, stream>>>(part, pscan, NB);
    k_offsets<<<NB, 256, 0, stream>>>(cnt, pscan, x, offs, dinv, meta);
    k_fill<<<NE / 256, 256, 0, stream>>>(e_src, e_dst, offs, fill, dinv, csre);

    // --- layer 0: gemm gathers A-rows straight from emb via x (h0 never materialized) ---
    hgemm<8, false, false, false, false, true><<<dim3(NN / 128, 1), 256, 0, stream>>>(
        emb, nullptr, nullptr, bt_hi + OFF_GCN, bt_lo + OFF_GCN,
        nullptr, hw, nullptr, FEAT, FEAT, x);
    // agg0: residual rows from emb[meta.w] -> h1 in hB
    k_agg<<<NN / 16, 256, 0, stream>>>(hw, nullptr, meta, csre, gb + 0 * FEAT, hB, emb);

    // --- layers 1..3: gemm(hin->hw) + agg(hw,hin->hout), ping-pong hB/hA ---
    float* hin = hB;
    float* hout = hA;
    for (int L = 1; L < 4; L++) {
        hgemm<8, false, false, false, false, false><<<dim3(NN / 128, 1), 256, 0, stream>>>(
            hin, nullptr, nullptr, bt_hi + OFF_GCN + L * 16384, bt_lo + OFF_GCN + L * 16384,
            nullptr, hw, nullptr, FEAT, FEAT, nullptr);
        k_agg<<<NN / 16, 256, 0, stream>>>(hw, hin, meta, csre, gb + (size_t)L * FEAT,
                                           hout, nullptr);
        float* t = hin; hin = hout; hout = t;
    }
    // h4 in hin (== hA)

    // --- layer 4: full gemm, selective agg (only the 2560 pair-phase rows) -> hq ---
    hgemm<8, false, false, false, false, false><<<dim3(NN / 128, 1), 256, 0, stream>>>(
        hin, nullptr, nullptr, bt_hi + OFF_GCN + 4 * 16384, bt_lo + OFF_GCN + 4 * 16384,
        nullptr, hw, nullptr, FEAT, FEAT, nullptr);
    k_aggq<<<(BATCH * NQ) / 8, 256, 0, stream>>>(hw, hin, meta, csre,
                                                 gb + 4 * (size_t)FEAT, hq);

    // --- pair MLP ---
    // combined P0: Abuf = hq@mw0_top + mb0 ; Bbuf = hq@mw0_bot   (M=2560, K=128, N=512)
    hgemm<8, false, false, true, false, false><<<dim3(20, 4), 256, 0, stream>>>(
        hq, nullptr, nullptr, bt_hi + OFF_P0, bt_lo + OFF_P0, mb0, Abuf, Bbuf, 512, 128, nullptr);
    // L1 fused pair0: A[p,:] = lrelu(Abuf[b,i,:] + Bbuf[b,j,:]) ; [51200,256]@[256,128]
    hgemm<8, true, true, false, true, false><<<dim3(NPAIR / 128, 1), 256, 0, stream>>>(
        nullptr, Abuf, Bbuf, bt_hi + OFF_M1, bt_lo + OFF_M1, mb1, X1, nullptr, 128, 256, nullptr);
    // L2: [51200,128] @ [128,128]
    hgemm<8, true, true, false, false, false><<<dim3(NPAIR / 128, 1), 256, 0, stream>>>(
        X1, nullptr, nullptr, bt_hi + OFF_M2, bt_lo + OFF_M2, mb2, X2, nullptr, 128, 128, nullptr);
    // L3: [51200,128] @ [128,64]
    hgemm<4, true, true, false, false, false><<<dim3(NPAIR / 128, 1), 256, 0, stream>>>(
        X2, nullptr, nullptr, bt_hi + OFF_M3, bt_lo + OFF_M3, mb3, X3, nullptr, 64, 128, nullptr);
    // L4: [51200,64] @ [64,64]
    hgemm<4, true, true, false, false, false><<<dim3(NPAIR / 128, 1), 256, 0, stream>>>(
        X3, nullptr, nullptr, bt_hi + OFF_M4, bt_lo + OFF_M4, mb4, X4, nullptr, 64, 64, nullptr);
    // L5 + symmetrize
    k_lastsym<<<BATCH, 256, 0, stream>>>(X4, mw5, mb5, out);
}